// Round 7
// baseline (435.557 us; speedup 1.0000x reference)
//
#include <hip/hip_runtime.h>

typedef __attribute__((ext_vector_type(8))) short bf16x8;
typedef __attribute__((ext_vector_type(4))) float f32x4;

__device__ __forceinline__ unsigned short f2bf(float f) {
    union { float f; unsigned u; } v; v.f = f;
    unsigned r = (v.u + 0x7FFFu + ((v.u >> 16) & 1u)) >> 16;   // round-to-nearest-even
    return (unsigned short)r;
}
__device__ __forceinline__ unsigned pack2bf(float a, float b) {
    return (unsigned)f2bf(a) | ((unsigned)f2bf(b) << 16);
}
__device__ __forceinline__ float bflo(unsigned u) { union { unsigned u; float f; } v; v.u = u << 16; return v.f; }
__device__ __forceinline__ float bfhi(unsigned u) { union { unsigned u; float f; } v; v.u = u & 0xffff0000u; return v.f; }

// ---------------- K0: mean-pool over T=4 + bf16 cast, padded [Mpad][320] ----------------
__global__ void pool_kernel(const float* __restrict__ x, unsigned short* __restrict__ xm,
                            int N, int Mpad) {
    int tid = blockIdx.x * 256 + threadIdx.x;
    if (tid >= Mpad * 40) return;
    int n = tid / 40, k8 = tid % 40;
    int k = k8 * 8;
    float v[8] = {0.f,0.f,0.f,0.f,0.f,0.f,0.f,0.f};
    if (n < N && k < 300) {
        const float* xp = x + (size_t)n * 1200 + k;
        #pragma unroll
        for (int t = 0; t < 4; ++t) {
            const float4 lo = *(const float4*)(xp + t * 300);
            v[0] += lo.x; v[1] += lo.y; v[2] += lo.z; v[3] += lo.w;
            if (k + 4 < 300) {   // k==296 tail: cols 300..303 stay zero
                const float4 hi = *(const float4*)(xp + t * 300 + 4);
                v[4] += hi.x; v[5] += hi.y; v[6] += hi.z; v[7] += hi.w;
            }
        }
    }
    union { unsigned short u[8]; bf16x8 vec; } p;
    #pragma unroll
    for (int j = 0; j < 8; ++j) p.u[j] = f2bf(v[j] * 0.25f);
    *(bf16x8*)(xm + (size_t)tid * 8) = p.vec;   // tid*8 == n*320 + k
}

// ---------------- setup: zero counters + weight prep ----------------
// W [300][300] f32 -> staged bf16 layout Ws[ks][col][kk]: ks=k/32 (10 steps), col<304, kk=k%32.
__global__ void setup_kernel(const float* __restrict__ W1, const float* __restrict__ b1,
                             const float* __restrict__ W2, const float* __restrict__ b2,
                             unsigned short* __restrict__ Ws1, unsigned short* __restrict__ Ws2,
                             float* __restrict__ bp1, float* __restrict__ bp2,
                             int* __restrict__ deg, int* __restrict__ cnt, int* __restrict__ cur, int N) {
    int tid = blockIdx.x * 256 + threadIdx.x;
    if (tid < N) { deg[tid] = 0; cnt[tid] = 0; cur[tid] = 0; }
    if (tid < 304 * 320) {
        int c = tid / 320, k = tid % 320;
        int ks = k / 32, kk = k % 32;
        int dst = ks * 9728 + c * 32 + kk;       // 9728 = 304*32 ushorts per K-step
        bool in = (c < 300) && (k < 300);
        Ws1[dst] = f2bf(in ? W1[c * 300 + k] : 0.f);
        Ws2[dst] = f2bf(in ? W2[c * 300 + k] : 0.f);
        if (tid < 304) { bp1[tid] = tid < 300 ? b1[tid] : 0.f; bp2[tid] = tid < 300 ? b2[tid] : 0.f; }
    }
}

// ---------------- degree (row/source) + in-degree counts (col/dest) ----------------
__global__ void degcnt_kernel(const int* __restrict__ ei, int E,
                              int* __restrict__ deg, int* __restrict__ cnt) {
    int e = blockIdx.x * 256 + threadIdx.x;
    if (e >= E) return;
    atomicAdd(&deg[ei[e]], 1);        // row
    atomicAdd(&cnt[ei[E + e]], 1);    // col
}

// ---------------- coalesced 3-phase scan: cnt -> indptr ----------------
__global__ void scanA_kernel(const int* __restrict__ cnt, int* __restrict__ bsum, int N) {
    __shared__ int sm[256];
    int i = blockIdx.x * 256 + threadIdx.x;
    sm[threadIdx.x] = (i < N) ? cnt[i] : 0;
    __syncthreads();
    for (int off = 128; off > 0; off >>= 1) {
        if (threadIdx.x < off) sm[threadIdx.x] += sm[threadIdx.x + off];
        __syncthreads();
    }
    if (threadIdx.x == 0) bsum[blockIdx.x] = sm[0];
}

__global__ void scanB_kernel(int* __restrict__ bsum, int nb, int* __restrict__ indptr, int N) {
    __shared__ int sm[256];
    int t = threadIdx.x;
    int v = (t < nb) ? bsum[t] : 0;
    sm[t] = v; __syncthreads();
    for (int off = 1; off < 256; off <<= 1) {
        int u = (t >= off) ? sm[t - off] : 0;
        __syncthreads();
        sm[t] += u;
        __syncthreads();
    }
    if (t < nb) bsum[t] = sm[t] - v;          // exclusive block offsets
    if (t == 255) indptr[N] = sm[255];        // total = E
}

__global__ void scanC_kernel(const int* __restrict__ cnt, const int* __restrict__ bsum,
                             int* __restrict__ indptr, const int* __restrict__ deg,
                             float* __restrict__ dis, int N) {
    __shared__ int sm[256];
    int i = blockIdx.x * 256 + threadIdx.x;
    int c = (i < N) ? cnt[i] : 0;
    sm[threadIdx.x] = c; __syncthreads();
    for (int off = 1; off < 256; off <<= 1) {
        int u = (threadIdx.x >= off) ? sm[threadIdx.x - off] : 0;
        __syncthreads();
        sm[threadIdx.x] += u;
        __syncthreads();
    }
    if (i < N) {
        indptr[i] = bsum[blockIdx.x] + sm[threadIdx.x] - c;   // exclusive prefix
        dis[i] = 1.0f / sqrtf((float)(deg[i] + 1));           // +1 self-loop
    }
}

// ---------------- CSR fill: csr[indptr[col]+slot] = row ----------------
__global__ void fill_kernel(const int* __restrict__ ei, int E,
                            const int* __restrict__ indptr, int* __restrict__ cur,
                            int* __restrict__ csr) {
    int e = blockIdx.x * 256 + threadIdx.x;
    if (e >= E) return;
    int r = ei[e], c = ei[E + e];
    int pos = indptr[c] + atomicAdd(&cur[c], 1);
    csr[pos] = r;
}

// ---------------- persistent-W GEMM: g[n][o] = bf16(dis[n]*(A@W^T + b)) ----------------
// Round 5/6 disease: with BM=64, every block re-staged all 194KB of W from L2 per pass
// (10 panels x 2 barriers x vmcnt drain each) -> ~98us/gemm at ~4% MfmaUtil.
// Fix: split cols 304 = 160(NCF=10) + 144(NCF=9); each half-W fits LDS (100/92 KB).
// Grid = 256 blocks (1/CU). Block stages its half-W ONCE, then grid-strides over
// 64-row tiles with ZERO barriers in the K-loop: A prefetched 10-deep per tile,
// B-fragments from resident LDS (dword perm l15*16+lhi*4 covers 0..255 -> conflict-free).
template<int NCF>
__global__ __launch_bounds__(256, 1) void gemm_persist(
    const unsigned short* __restrict__ A, const unsigned short* __restrict__ Ws,
    const float* __restrict__ bp, const float* __restrict__ dis,
    unsigned short* __restrict__ g, int N, int colbase, int ntiles)
{
    __shared__ __align__(16) unsigned short lds[NCF * 5120];   // 10 panels x NCF*512 ushorts
    const int t = threadIdx.x;
    const int lane = t & 63;
    const int wave = t >> 6;
    const int l15 = lane & 15, lhi = lane >> 4;

    // ---- stage half-W once (NCF*640 16B-chunks), 5-deep batches ----
    {
        constexpr int C16 = NCF * 640;       // 16B chunks total (6400 / 5760)
        constexpr int PANEL16 = NCF * 64;    // 16B chunks per panel-half
        const uint4* gsrc = (const uint4*)Ws;        // full panel = 1216 chunks
        uint4* ldst = (uint4*)lds;
        for (int base = 0; base < C16; base += 1280) {
            uint4 v[5];
            #pragma unroll
            for (int q = 0; q < 5; ++q) {
                int c16 = base + q * 256 + t;
                if (c16 < C16) {
                    int ks = c16 / PANEL16, rem = c16 - ks * PANEL16;
                    v[q] = gsrc[ks * 1216 + colbase * 4 + rem];
                }
            }
            #pragma unroll
            for (int q = 0; q < 5; ++q) {
                int c16 = base + q * 256 + t;
                if (c16 < C16) ldst[c16] = v[q];
            }
        }
    }
    __syncthreads();

    // ---- grid-stride over 64-row tiles; K-loop barrier-free ----
    for (int tile = blockIdx.x; tile < ntiles; tile += 256) {
        const int row0 = tile * 64 + wave * 16;
        const unsigned short* Ap = A + (size_t)(row0 + l15) * 320 + lhi * 8;

        bf16x8 a[10];
        #pragma unroll
        for (int ks = 0; ks < 10; ++ks) a[ks] = *(const bf16x8*)(Ap + ks * 32);

        f32x4 acc[NCF];
        #pragma unroll
        for (int i = 0; i < NCF; ++i) acc[i] = (f32x4){0.f,0.f,0.f,0.f};

        #pragma unroll
        for (int ks = 0; ks < 10; ++ks) {
            const unsigned short* lb = lds + ks * (NCF * 512) + l15 * 32 + lhi * 8;
            #pragma unroll
            for (int cf = 0; cf < NCF; ++cf) {
                bf16x8 b = *(const bf16x8*)(lb + cf * 512);
                acc[cf] = __builtin_amdgcn_mfma_f32_16x16x32_bf16(a[ks], b, acc[cf], 0, 0, 0);
            }
        }

        const int n0 = row0 + lhi * 4;
        float dd[4];
        #pragma unroll
        for (int r = 0; r < 4; ++r) dd[r] = (n0 + r < N) ? dis[n0 + r] : 0.f;
        #pragma unroll
        for (int cf = 0; cf < NCF; ++cf) {
            int o = colbase + cf * 16 + l15;
            if (o < 300) {
                float bo = bp[o];
                #pragma unroll
                for (int r = 0; r < 4; ++r)
                    if (n0 + r < N) g[(size_t)(n0 + r) * 320 + o] = f2bf(dd[r] * (acc[cf][r] + bo));
            }
        }
    }
}

// ---------------- propagate (bf16 g, pre-scaled by dis): out[i] = dis[i]*(g[i]+sum g[src]) ----------------
// One-issue row gather: padded row = 640B = 40 uint4; lanes 0..37 each read ONE uint4.
// Lane 37's top 8B are pad-col poison, masked at write. x4 neighbor unroll for MLP.
// MODE 0: f32 compact [N][300] to d_out. MODE 1: leaky_relu + bf16 padded [Mpad][320].
template<int MODE>
__global__ void prop_kernel(const unsigned short* __restrict__ g, const int* __restrict__ indptr,
                            const int* __restrict__ csr, const float* __restrict__ dis,
                            void* __restrict__ outp, int N, int Mpad) {
    int wave = threadIdx.x >> 6;
    int lane = threadIdx.x & 63;
    int n = blockIdx.x * 4 + wave;
    if (n >= (MODE ? Mpad : N)) return;
    const bool act = lane < 38;                    // 38*16B = 608B >= 600B of real cols
    float aL[4] = {0.f,0.f,0.f,0.f}, aH[4] = {0.f,0.f,0.f,0.f};
    if (n < N) {
        if (act) {
            uint4 u = *((const uint4*)(g + (size_t)n * 320) + lane);
            aL[0] = bflo(u.x); aH[0] = bfhi(u.x);
            aL[1] = bflo(u.y); aH[1] = bfhi(u.y);
            aL[2] = bflo(u.z); aH[2] = bfhi(u.z);
            aL[3] = bflo(u.w); aH[3] = bfhi(u.w);
        }
        int beg = indptr[n], end = indptr[n + 1];
        int j = beg;
        for (; j + 4 <= end; j += 4) {
            int s0 = csr[j], s1 = csr[j+1], s2 = csr[j+2], s3 = csr[j+3];
            const uint4* p0 = (const uint4*)(g + (size_t)s0 * 320) + lane;
            const uint4* p1 = (const uint4*)(g + (size_t)s1 * 320) + lane;
            const uint4* p2 = (const uint4*)(g + (size_t)s2 * 320) + lane;
            const uint4* p3 = (const uint4*)(g + (size_t)s3 * 320) + lane;
            if (act) {
                uint4 u0 = *p0, u1 = *p1, u2 = *p2, u3 = *p3;
                aL[0] += bflo(u0.x) + bflo(u1.x) + bflo(u2.x) + bflo(u3.x);
                aH[0] += bfhi(u0.x) + bfhi(u1.x) + bfhi(u2.x) + bfhi(u3.x);
                aL[1] += bflo(u0.y) + bflo(u1.y) + bflo(u2.y) + bflo(u3.y);
                aH[1] += bfhi(u0.y) + bfhi(u1.y) + bfhi(u2.y) + bfhi(u3.y);
                aL[2] += bflo(u0.z) + bflo(u1.z) + bflo(u2.z) + bflo(u3.z);
                aH[2] += bfhi(u0.z) + bfhi(u1.z) + bfhi(u2.z) + bfhi(u3.z);
                aL[3] += bflo(u0.w) + bflo(u1.w) + bflo(u2.w) + bflo(u3.w);
                aH[3] += bfhi(u0.w) + bfhi(u1.w) + bfhi(u2.w) + bfhi(u3.w);
            }
        }
        for (; j < end; ++j) {
            const uint4* ps = (const uint4*)(g + (size_t)csr[j] * 320) + lane;
            if (act) {
                uint4 u = *ps;
                aL[0] += bflo(u.x); aH[0] += bfhi(u.x);
                aL[1] += bflo(u.y); aH[1] += bfhi(u.y);
                aL[2] += bflo(u.z); aH[2] += bfhi(u.z);
                aL[3] += bflo(u.w); aH[3] += bfhi(u.w);
            }
        }
        float dn = dis[n];
        #pragma unroll
        for (int i = 0; i < 4; ++i) { aL[i] *= dn; aH[i] *= dn; }
    }
    if (MODE == 0) {
        // lane l covers f32 cols 8l..8l+7; lane 37 only 296..299 valid
        float* out = (float*)outp + (size_t)n * 300 + lane * 8;
        if (lane < 37) {
            float4 f0 = {aL[0], aH[0], aL[1], aH[1]};
            float4 f1 = {aL[2], aH[2], aL[3], aH[3]};
            *(float4*)out = f0;
            *(float4*)(out + 4) = f1;
        } else if (lane == 37) {
            float4 f0 = {aL[0], aH[0], aL[1], aH[1]};
            *(float4*)out = f0;
        }
    } else {
        uint4* h = (uint4*)((unsigned*)outp + (size_t)n * 160) + lane;
        if (lane < 40) {
            uint4 w = {0u, 0u, 0u, 0u};
            if (act) {
                float vL, vH;
                vL = aL[0]; vL = vL > 0.f ? vL : 0.01f * vL;
                vH = aH[0]; vH = vH > 0.f ? vH : 0.01f * vH;
                w.x = pack2bf(vL, vH);
                vL = aL[1]; vL = vL > 0.f ? vL : 0.01f * vL;
                vH = aH[1]; vH = vH > 0.f ? vH : 0.01f * vH;
                w.y = pack2bf(vL, vH);
                vL = aL[2]; vL = vL > 0.f ? vL : 0.01f * vL;
                vH = aH[2]; vH = vH > 0.f ? vH : 0.01f * vH;
                w.z = pack2bf(vL, vH);
                vL = aL[3]; vL = vL > 0.f ? vL : 0.01f * vL;
                vH = aH[3]; vH = vH > 0.f ? vH : 0.01f * vH;
                w.w = pack2bf(vL, vH);
                if (lane == 37) { w.z = 0u; w.w = 0u; }   // cols 300..303 = K-pad
            }
            *h = w;                                       // lanes 38,39 zero cols 304..319
        }
    }
}

extern "C" void kernel_launch(void* const* d_in, const int* in_sizes, int n_in,
                              void* d_out, int out_size, void* d_ws, size_t ws_size,
                              hipStream_t stream) {
    const float* x  = (const float*)d_in[0];
    const int*   ei = (const int*)d_in[1];
    const float* W1 = (const float*)d_in[2];
    const float* b1 = (const float*)d_in[3];
    const float* W2 = (const float*)d_in[4];
    const float* b2 = (const float*)d_in[5];
    float* out = (float*)d_out;

    const int N = in_sizes[0] / 1200;     // 50000
    const int E = in_sizes[1] / 2;        // 250000
    const int Mpad = ((N + 127) / 128) * 128;   // 50048 (multiple of 64)
    const int NB = (N + 255) / 256;       // 196 scan tiles
    const int ntiles = Mpad / 64;         // 782 row-tiles

    // ---- carve workspace (256B aligned) ----
    char* p = (char*)d_ws;
    auto carve = [&](size_t bytes) -> char* {
        char* r = p; p += (bytes + 255) & ~(size_t)255; return r;
    };
    unsigned short* xm   = (unsigned short*)carve((size_t)Mpad * 320 * 2);  // 32 MB
    unsigned short* g1   = (unsigned short*)carve((size_t)Mpad * 320 * 2);  // 32 MB
    unsigned short* hb   = (unsigned short*)carve((size_t)Mpad * 320 * 2);  // 32 MB
    unsigned short* g2   = (unsigned short*)carve((size_t)Mpad * 320 * 2);  // 32 MB
    float* dis           = (float*)carve((size_t)N * 4);
    int* deg             = (int*)carve((size_t)N * 4);
    int* cnt             = (int*)carve((size_t)N * 4);
    int* indptr          = (int*)carve((size_t)(N + 1) * 4);
    int* cur             = (int*)carve((size_t)N * 4);
    int* csr             = (int*)carve((size_t)E * 4);
    int* bsum            = (int*)carve(256 * 4);
    unsigned short* Ws1  = (unsigned short*)carve(304 * 320 * 2);   // staged [10][304][32]
    unsigned short* Ws2  = (unsigned short*)carve(304 * 320 * 2);
    float* bp1           = (float*)carve(304 * 4);
    float* bp2           = (float*)carve(304 * 4);

    setup_kernel <<<(304 * 320 + 255) / 256, 256, 0, stream>>>(W1, b1, W2, b2, Ws1, Ws2, bp1, bp2,
                                                               deg, cnt, cur, N);
    pool_kernel  <<<(Mpad * 40 + 255) / 256, 256, 0, stream>>>(x, xm, N, Mpad);
    degcnt_kernel<<<(E + 255) / 256, 256, 0, stream>>>(ei, E, deg, cnt);
    scanA_kernel <<<NB, 256, 0, stream>>>(cnt, bsum, N);
    scanB_kernel <<<1, 256, 0, stream>>>(bsum, NB, indptr, N);
    scanC_kernel <<<NB, 256, 0, stream>>>(cnt, bsum, indptr, deg, dis, N);
    fill_kernel  <<<(E + 255) / 256, 256, 0, stream>>>(ei, E, indptr, cur, csr);

    // layer 1: g1 = bf16(dis*(xm@W1^T + b1)); prop+leaky -> hb (bf16 padded)
    gemm_persist<10><<<256, 256, 0, stream>>>(xm, Ws1, bp1, dis, g1, N, 0,   ntiles);
    gemm_persist<9> <<<256, 256, 0, stream>>>(xm, Ws1, bp1, dis, g1, N, 160, ntiles);
    prop_kernel<1><<<Mpad / 4, 256, 0, stream>>>(g1, indptr, csr, dis, hb, N, Mpad);
    // layer 2: g2 = bf16(dis*(hb@W2^T + b2)); final prop -> d_out (f32)
    gemm_persist<10><<<256, 256, 0, stream>>>(hb, Ws2, bp2, dis, g2, N, 0,   ntiles);
    gemm_persist<9> <<<256, 256, 0, stream>>>(hb, Ws2, bp2, dis, g2, N, 160, ntiles);
    prop_kernel<0><<<(N + 3) / 4, 256, 0, stream>>>(g2, indptr, csr, dis, out, N, Mpad);
}

// Round 8
// 373.147 us; speedup vs baseline: 1.1673x; 1.1673x over previous
//
#include <hip/hip_runtime.h>

typedef __attribute__((ext_vector_type(8))) short bf16x8;
typedef __attribute__((ext_vector_type(4))) float f32x4;

__device__ __forceinline__ unsigned short f2bf(float f) {
    union { float f; unsigned u; } v; v.f = f;
    unsigned r = (v.u + 0x7FFFu + ((v.u >> 16) & 1u)) >> 16;   // round-to-nearest-even
    return (unsigned short)r;
}
__device__ __forceinline__ unsigned pack2bf(float a, float b) {
    return (unsigned)f2bf(a) | ((unsigned)f2bf(b) << 16);
}
__device__ __forceinline__ float bflo(unsigned u) { union { unsigned u; float f; } v; v.u = u << 16; return v.f; }
__device__ __forceinline__ float bfhi(unsigned u) { union { unsigned u; float f; } v; v.u = u & 0xffff0000u; return v.f; }

// ---------------- K0: mean-pool over T=4 + bf16 cast, padded [Mpad][320] ----------------
__global__ void pool_kernel(const float* __restrict__ x, unsigned short* __restrict__ xm,
                            int N, int Mpad) {
    int tid = blockIdx.x * 256 + threadIdx.x;
    if (tid >= Mpad * 40) return;
    int n = tid / 40, k8 = tid % 40;
    int k = k8 * 8;
    float v[8] = {0.f,0.f,0.f,0.f,0.f,0.f,0.f,0.f};
    if (n < N && k < 300) {
        const float* xp = x + (size_t)n * 1200 + k;
        #pragma unroll
        for (int t = 0; t < 4; ++t) {
            const float4 lo = *(const float4*)(xp + t * 300);
            v[0] += lo.x; v[1] += lo.y; v[2] += lo.z; v[3] += lo.w;
            if (k + 4 < 300) {   // k==296 tail: cols 300..303 stay zero
                const float4 hi = *(const float4*)(xp + t * 300 + 4);
                v[4] += hi.x; v[5] += hi.y; v[6] += hi.z; v[7] += hi.w;
            }
        }
    }
    union { unsigned short u[8]; bf16x8 vec; } p;
    #pragma unroll
    for (int j = 0; j < 8; ++j) p.u[j] = f2bf(v[j] * 0.25f);
    *(bf16x8*)(xm + (size_t)tid * 8) = p.vec;   // tid*8 == n*320 + k
}

// ---------------- setup: zero counters + weight prep ----------------
// W [300][300] f32 -> staged bf16 layout Ws[ks][col][kk]: ks=k/32 (10 steps), col<304, kk=k%32.
__global__ void setup_kernel(const float* __restrict__ W1, const float* __restrict__ b1,
                             const float* __restrict__ W2, const float* __restrict__ b2,
                             unsigned short* __restrict__ Ws1, unsigned short* __restrict__ Ws2,
                             float* __restrict__ bp1, float* __restrict__ bp2,
                             int* __restrict__ deg, int* __restrict__ cnt, int* __restrict__ cur, int N) {
    int tid = blockIdx.x * 256 + threadIdx.x;
    if (tid < N) { deg[tid] = 0; cnt[tid] = 0; cur[tid] = 0; }
    if (tid < 304 * 320) {
        int c = tid / 320, k = tid % 320;
        int ks = k / 32, kk = k % 32;
        int dst = ks * 9728 + c * 32 + kk;       // 9728 = 304*32 ushorts per K-step
        bool in = (c < 300) && (k < 300);
        Ws1[dst] = f2bf(in ? W1[c * 300 + k] : 0.f);
        Ws2[dst] = f2bf(in ? W2[c * 300 + k] : 0.f);
        if (tid < 304) { bp1[tid] = tid < 300 ? b1[tid] : 0.f; bp2[tid] = tid < 300 ? b2[tid] : 0.f; }
    }
}

// ---------------- degree (row/source) + in-degree counts (col/dest) ----------------
__global__ void degcnt_kernel(const int* __restrict__ ei, int E,
                              int* __restrict__ deg, int* __restrict__ cnt) {
    int e = blockIdx.x * 256 + threadIdx.x;
    if (e >= E) return;
    atomicAdd(&deg[ei[e]], 1);        // row
    atomicAdd(&cnt[ei[E + e]], 1);    // col
}

// ---------------- coalesced 3-phase scan: cnt -> indptr ----------------
__global__ void scanA_kernel(const int* __restrict__ cnt, int* __restrict__ bsum, int N) {
    __shared__ int sm[256];
    int i = blockIdx.x * 256 + threadIdx.x;
    sm[threadIdx.x] = (i < N) ? cnt[i] : 0;
    __syncthreads();
    for (int off = 128; off > 0; off >>= 1) {
        if (threadIdx.x < off) sm[threadIdx.x] += sm[threadIdx.x + off];
        __syncthreads();
    }
    if (threadIdx.x == 0) bsum[blockIdx.x] = sm[0];
}

__global__ void scanB_kernel(int* __restrict__ bsum, int nb, int* __restrict__ indptr, int N) {
    __shared__ int sm[256];
    int t = threadIdx.x;
    int v = (t < nb) ? bsum[t] : 0;
    sm[t] = v; __syncthreads();
    for (int off = 1; off < 256; off <<= 1) {
        int u = (t >= off) ? sm[t - off] : 0;
        __syncthreads();
        sm[t] += u;
        __syncthreads();
    }
    if (t < nb) bsum[t] = sm[t] - v;          // exclusive block offsets
    if (t == 255) indptr[N] = sm[255];        // total = E
}

__global__ void scanC_kernel(const int* __restrict__ cnt, const int* __restrict__ bsum,
                             int* __restrict__ indptr, const int* __restrict__ deg,
                             float* __restrict__ dis, int N) {
    __shared__ int sm[256];
    int i = blockIdx.x * 256 + threadIdx.x;
    int c = (i < N) ? cnt[i] : 0;
    sm[threadIdx.x] = c; __syncthreads();
    for (int off = 1; off < 256; off <<= 1) {
        int u = (threadIdx.x >= off) ? sm[threadIdx.x - off] : 0;
        __syncthreads();
        sm[threadIdx.x] += u;
        __syncthreads();
    }
    if (i < N) {
        indptr[i] = bsum[blockIdx.x] + sm[threadIdx.x] - c;   // exclusive prefix
        dis[i] = 1.0f / sqrtf((float)(deg[i] + 1));           // +1 self-loop
    }
}

// ---------------- CSR fill: csr[indptr[col]+slot] = row ----------------
__global__ void fill_kernel(const int* __restrict__ ei, int E,
                            const int* __restrict__ indptr, int* __restrict__ cur,
                            int* __restrict__ csr) {
    int e = blockIdx.x * 256 + threadIdx.x;
    if (e >= E) return;
    int r = ei[e], c = ei[E + e];
    int pos = indptr[c] + atomicAdd(&cur[c], 1);
    csr[pos] = r;
}

// ---------------- GEMM (round-6 dbuf structure), REP = in-kernel repeat ----------------
// REP=2 is a DIAGNOSTIC: recompute the identical result twice (acc re-zeroed, panel 0
// re-staged per rep; second rep writes identical g) so the dispatch exceeds the 131us
// fillBuffer floor and surfaces real counters (MfmaUtil/Occupancy/BankConflict/FETCH).
template<int REP>
__global__ __launch_bounds__(256) void gemm_kernel(
    const unsigned short* __restrict__ A, const unsigned short* __restrict__ Ws,
    const float* __restrict__ bp, const float* __restrict__ dis,
    unsigned short* __restrict__ g, int N)
{
    __shared__ __align__(16) unsigned short lds[2][9728];   // 2 x 19456B
    const int t = threadIdx.x;
    const int lane = t & 63;
    const int wave = t >> 6;
    const int l15 = lane & 15, lhi = lane >> 4;
    const int rowBase = blockIdx.x * 64 + wave * 16;

    const unsigned short* Ap = A + (size_t)(rowBase + l15) * 320 + lhi * 8;
    const uint4* Wsrc = (const uint4*)Ws;        // 16B chunks; 1216 chunks per K-step

    f32x4 acc[19];
    for (int rep = 0; rep < REP; ++rep) {
        #pragma unroll
        for (int i = 0; i < 19; ++i) acc[i] = (f32x4){0.f,0.f,0.f,0.f};

        uint4 st[5];
        {   // prologue: stage panel 0 into buf0 (safe vs prior rep: last rep read buf1 at ks=9)
            const uint4* s = Wsrc;
            #pragma unroll
            for (int r = 0; r < 4; ++r) st[r] = s[t + 256 * r];
            if (t < 192) st[4] = s[t + 1024];
            __syncthreads();
            uint4* d = (uint4*)lds[0];
            #pragma unroll
            for (int r = 0; r < 4; ++r) d[t + 256 * r] = st[r];
            if (t < 192) d[t + 1024] = st[4];
        }
        __syncthreads();

        #pragma unroll 2
        for (int ks = 0; ks < 10; ++ks) {
            if (ks < 9) {                              // issue next-panel loads early
                const uint4* s = Wsrc + (ks + 1) * 1216;
                #pragma unroll
                for (int r = 0; r < 4; ++r) st[r] = s[t + 256 * r];
                if (t < 192) st[4] = s[t + 1024];
            }
            bf16x8 a = *(const bf16x8*)(Ap + ks * 32);
            const unsigned short* lb = lds[ks & 1] + l15 * 32 + lhi * 8;
            #pragma unroll
            for (int cf = 0; cf < 19; ++cf) {
                bf16x8 b = *(const bf16x8*)(lb + cf * 512);   // col cf*16+l15, k-off lhi*8
                acc[cf] = __builtin_amdgcn_mfma_f32_16x16x32_bf16(a, b, acc[cf], 0, 0, 0);
            }
            if (ks < 9) {
                __syncthreads();                       // all waves done reading buf[(ks+1)&1]
                uint4* d = (uint4*)lds[(ks + 1) & 1];
                #pragma unroll
                for (int r = 0; r < 4; ++r) d[t + 256 * r] = st[r];
                if (t < 192) d[t + 1024] = st[4];
                __syncthreads();                       // staged panel visible
            }
        }
    }

    const int n0 = rowBase + lhi * 4;
    float dd[4];
    #pragma unroll
    for (int r = 0; r < 4; ++r) dd[r] = (n0 + r < N) ? dis[n0 + r] : 0.f;
    #pragma unroll
    for (int cf = 0; cf < 19; ++cf) {
        int o = cf * 16 + l15;
        if (o < 300) {
            float bo = bp[o];
            #pragma unroll
            for (int r = 0; r < 4; ++r)
                if (n0 + r < N) g[(size_t)(n0 + r) * 320 + o] = f2bf(dd[r] * (acc[cf][r] + bo));
        }
    }
}

// ---------------- GEMM v2 (A/B candidate): 512 threads / 8 waves / BM=128 ----------------
// Same dbuf LDS; halves W re-staging traffic (391 blocks vs 782) and doubles
// waves-per-block. Blind A/B vs round-6 via total duration.
__global__ __launch_bounds__(512) void gemm_kernel2(
    const unsigned short* __restrict__ A, const unsigned short* __restrict__ Ws,
    const float* __restrict__ bp, const float* __restrict__ dis,
    unsigned short* __restrict__ g, int N)
{
    __shared__ __align__(16) unsigned short lds[2][9728];   // 2 x 19456B
    const int t = threadIdx.x;                // 0..511
    const int lane = t & 63;
    const int wave = t >> 6;                  // 0..7
    const int l15 = lane & 15, lhi = lane >> 4;
    const int rowBase = blockIdx.x * 128 + wave * 16;

    f32x4 acc[19];
    #pragma unroll
    for (int i = 0; i < 19; ++i) acc[i] = (f32x4){0.f,0.f,0.f,0.f};

    const unsigned short* Ap = A + (size_t)(rowBase + l15) * 320 + lhi * 8;
    const uint4* Wsrc = (const uint4*)Ws;

    uint4 st[3];
    {   // prologue: stage panel 0 (1216 chunks over 512 threads)
        const uint4* s = Wsrc;
        st[0] = s[t]; st[1] = s[t + 512];
        if (t < 192) st[2] = s[t + 1024];
        uint4* d = (uint4*)lds[0];
        d[t] = st[0]; d[t + 512] = st[1];
        if (t < 192) d[t + 1024] = st[2];
    }
    __syncthreads();

    #pragma unroll 2
    for (int ks = 0; ks < 10; ++ks) {
        if (ks < 9) {
            const uint4* s = Wsrc + (ks + 1) * 1216;
            st[0] = s[t]; st[1] = s[t + 512];
            if (t < 192) st[2] = s[t + 1024];
        }
        bf16x8 a = *(const bf16x8*)(Ap + ks * 32);
        const unsigned short* lb = lds[ks & 1] + l15 * 32 + lhi * 8;
        #pragma unroll
        for (int cf = 0; cf < 19; ++cf) {
            bf16x8 b = *(const bf16x8*)(lb + cf * 512);
            acc[cf] = __builtin_amdgcn_mfma_f32_16x16x32_bf16(a, b, acc[cf], 0, 0, 0);
        }
        if (ks < 9) {
            __syncthreads();
            uint4* d = (uint4*)lds[(ks + 1) & 1];
            d[t] = st[0]; d[t + 512] = st[1];
            if (t < 192) d[t + 1024] = st[2];
            __syncthreads();
        }
    }

    const int n0 = rowBase + lhi * 4;
    float dd[4];
    #pragma unroll
    for (int r = 0; r < 4; ++r) dd[r] = (n0 + r < N) ? dis[n0 + r] : 0.f;
    #pragma unroll
    for (int cf = 0; cf < 19; ++cf) {
        int o = cf * 16 + l15;
        if (o < 300) {
            float bo = bp[o];
            #pragma unroll
            for (int r = 0; r < 4; ++r)
                if (n0 + r < N) g[(size_t)(n0 + r) * 320 + o] = f2bf(dd[r] * (acc[cf][r] + bo));
        }
    }
}

// ---------------- propagate (bf16 g, pre-scaled by dis): out[i] = dis[i]*(g[i]+sum g[src]) ----------------
// One-issue row gather: padded row = 640B = 40 uint4; lanes 0..37 each read ONE uint4.
// Lane 37's top 8B are pad-col poison, masked at write. x4 neighbor unroll for MLP.
// MODE 0: f32 compact [N][300] to d_out. MODE 1: leaky_relu + bf16 padded [Mpad][320].
template<int MODE>
__global__ void prop_kernel(const unsigned short* __restrict__ g, const int* __restrict__ indptr,
                            const int* __restrict__ csr, const float* __restrict__ dis,
                            void* __restrict__ outp, int N, int Mpad) {
    int wave = threadIdx.x >> 6;
    int lane = threadIdx.x & 63;
    int n = blockIdx.x * 4 + wave;
    if (n >= (MODE ? Mpad : N)) return;
    const bool act = lane < 38;                    // 38*16B = 608B >= 600B of real cols
    float aL[4] = {0.f,0.f,0.f,0.f}, aH[4] = {0.f,0.f,0.f,0.f};
    if (n < N) {
        if (act) {
            uint4 u = *((const uint4*)(g + (size_t)n * 320) + lane);
            aL[0] = bflo(u.x); aH[0] = bfhi(u.x);
            aL[1] = bflo(u.y); aH[1] = bfhi(u.y);
            aL[2] = bflo(u.z); aH[2] = bfhi(u.z);
            aL[3] = bflo(u.w); aH[3] = bfhi(u.w);
        }
        int beg = indptr[n], end = indptr[n + 1];
        int j = beg;
        for (; j + 4 <= end; j += 4) {
            int s0 = csr[j], s1 = csr[j+1], s2 = csr[j+2], s3 = csr[j+3];
            const uint4* p0 = (const uint4*)(g + (size_t)s0 * 320) + lane;
            const uint4* p1 = (const uint4*)(g + (size_t)s1 * 320) + lane;
            const uint4* p2 = (const uint4*)(g + (size_t)s2 * 320) + lane;
            const uint4* p3 = (const uint4*)(g + (size_t)s3 * 320) + lane;
            if (act) {
                uint4 u0 = *p0, u1 = *p1, u2 = *p2, u3 = *p3;
                aL[0] += bflo(u0.x) + bflo(u1.x) + bflo(u2.x) + bflo(u3.x);
                aH[0] += bfhi(u0.x) + bfhi(u1.x) + bfhi(u2.x) + bfhi(u3.x);
                aL[1] += bflo(u0.y) + bflo(u1.y) + bflo(u2.y) + bflo(u3.y);
                aH[1] += bfhi(u0.y) + bfhi(u1.y) + bfhi(u2.y) + bfhi(u3.y);
                aL[2] += bflo(u0.z) + bflo(u1.z) + bflo(u2.z) + bflo(u3.z);
                aH[2] += bfhi(u0.z) + bfhi(u1.z) + bfhi(u2.z) + bfhi(u3.z);
                aL[3] += bflo(u0.w) + bflo(u1.w) + bflo(u2.w) + bflo(u3.w);
                aH[3] += bfhi(u0.w) + bfhi(u1.w) + bfhi(u2.w) + bfhi(u3.w);
            }
        }
        for (; j < end; ++j) {
            const uint4* ps = (const uint4*)(g + (size_t)csr[j] * 320) + lane;
            if (act) {
                uint4 u = *ps;
                aL[0] += bflo(u.x); aH[0] += bfhi(u.x);
                aL[1] += bflo(u.y); aH[1] += bfhi(u.y);
                aL[2] += bflo(u.z); aH[2] += bfhi(u.z);
                aL[3] += bflo(u.w); aH[3] += bfhi(u.w);
            }
        }
        float dn = dis[n];
        #pragma unroll
        for (int i = 0; i < 4; ++i) { aL[i] *= dn; aH[i] *= dn; }
    }
    if (MODE == 0) {
        // lane l covers f32 cols 8l..8l+7; lane 37 only 296..299 valid
        float* out = (float*)outp + (size_t)n * 300 + lane * 8;
        if (lane < 37) {
            float4 f0 = {aL[0], aH[0], aL[1], aH[1]};
            float4 f1 = {aL[2], aH[2], aL[3], aH[3]};
            *(float4*)out = f0;
            *(float4*)(out + 4) = f1;
        } else if (lane == 37) {
            float4 f0 = {aL[0], aH[0], aL[1], aH[1]};
            *(float4*)out = f0;
        }
    } else {
        uint4* h = (uint4*)((unsigned*)outp + (size_t)n * 160) + lane;
        if (lane < 40) {
            uint4 w = {0u, 0u, 0u, 0u};
            if (act) {
                float vL, vH;
                vL = aL[0]; vL = vL > 0.f ? vL : 0.01f * vL;
                vH = aH[0]; vH = vH > 0.f ? vH : 0.01f * vH;
                w.x = pack2bf(vL, vH);
                vL = aL[1]; vL = vL > 0.f ? vL : 0.01f * vL;
                vH = aH[1]; vH = vH > 0.f ? vH : 0.01f * vH;
                w.y = pack2bf(vL, vH);
                vL = aL[2]; vL = vL > 0.f ? vL : 0.01f * vL;
                vH = aH[2]; vH = vH > 0.f ? vH : 0.01f * vH;
                w.z = pack2bf(vL, vH);
                vL = aL[3]; vL = vL > 0.f ? vL : 0.01f * vL;
                vH = aH[3]; vH = vH > 0.f ? vH : 0.01f * vH;
                w.w = pack2bf(vL, vH);
                if (lane == 37) { w.z = 0u; w.w = 0u; }   // cols 300..303 = K-pad
            }
            *h = w;                                       // lanes 38,39 zero cols 304..319
        }
    }
}

extern "C" void kernel_launch(void* const* d_in, const int* in_sizes, int n_in,
                              void* d_out, int out_size, void* d_ws, size_t ws_size,
                              hipStream_t stream) {
    const float* x  = (const float*)d_in[0];
    const int*   ei = (const int*)d_in[1];
    const float* W1 = (const float*)d_in[2];
    const float* b1 = (const float*)d_in[3];
    const float* W2 = (const float*)d_in[4];
    const float* b2 = (const float*)d_in[5];
    float* out = (float*)d_out;

    const int N = in_sizes[0] / 1200;     // 50000
    const int E = in_sizes[1] / 2;        // 250000
    const int Mpad = ((N + 127) / 128) * 128;   // 50048 (multiple of 128)
    const int NB = (N + 255) / 256;       // 196 scan tiles

    // ---- carve workspace (256B aligned) ----
    char* p = (char*)d_ws;
    auto carve = [&](size_t bytes) -> char* {
        char* r = p; p += (bytes + 255) & ~(size_t)255; return r;
    };
    unsigned short* xm   = (unsigned short*)carve((size_t)Mpad * 320 * 2);  // 32 MB
    unsigned short* g1   = (unsigned short*)carve((size_t)Mpad * 320 * 2);  // 32 MB
    unsigned short* hb   = (unsigned short*)carve((size_t)Mpad * 320 * 2);  // 32 MB
    unsigned short* g2   = (unsigned short*)carve((size_t)Mpad * 320 * 2);  // 32 MB
    float* dis           = (float*)carve((size_t)N * 4);
    int* deg             = (int*)carve((size_t)N * 4);
    int* cnt             = (int*)carve((size_t)N * 4);
    int* indptr          = (int*)carve((size_t)(N + 1) * 4);
    int* cur             = (int*)carve((size_t)N * 4);
    int* csr             = (int*)carve((size_t)E * 4);
    int* bsum            = (int*)carve(256 * 4);
    unsigned short* Ws1  = (unsigned short*)carve(304 * 320 * 2);   // staged [10][304][32]
    unsigned short* Ws2  = (unsigned short*)carve(304 * 320 * 2);
    float* bp1           = (float*)carve(304 * 4);
    float* bp2           = (float*)carve(304 * 4);

    setup_kernel <<<(304 * 320 + 255) / 256, 256, 0, stream>>>(W1, b1, W2, b2, Ws1, Ws2, bp1, bp2,
                                                               deg, cnt, cur, N);
    pool_kernel  <<<(Mpad * 40 + 255) / 256, 256, 0, stream>>>(x, xm, N, Mpad);
    degcnt_kernel<<<(E + 255) / 256, 256, 0, stream>>>(ei, E, deg, cnt);
    scanA_kernel <<<NB, 256, 0, stream>>>(cnt, bsum, N);
    scanB_kernel <<<1, 256, 0, stream>>>(bsum, NB, indptr, N);
    scanC_kernel <<<NB, 256, 0, stream>>>(cnt, bsum, indptr, deg, dis, N);
    fill_kernel  <<<(E + 255) / 256, 256, 0, stream>>>(ei, E, indptr, cur, csr);

    // layer 1: REP=2 diagnostic gemm (visible in rocprof top-5); prop+leaky -> hb
    gemm_kernel<2><<<Mpad / 64, 256, 0, stream>>>(xm, Ws1, bp1, dis, g1, N);
    prop_kernel<1><<<Mpad / 4, 256, 0, stream>>>(g1, indptr, csr, dis, hb, N, Mpad);
    // layer 2: v2 candidate gemm (512t / BM=128); final prop -> d_out (f32)
    gemm_kernel2  <<<Mpad / 128, 512, 0, stream>>>(hb, Ws2, bp2, dis, g2, N);
    prop_kernel<0><<<(N + 3) / 4, 256, 0, stream>>>(g2, indptr, csr, dis, out, N, Mpad);
}

// Round 9
// 253.490 us; speedup vs baseline: 1.7182x; 1.4720x over previous
//
#include <hip/hip_runtime.h>

typedef __attribute__((ext_vector_type(8))) short bf16x8;
typedef __attribute__((ext_vector_type(4))) float f32x4;

__device__ __forceinline__ unsigned short f2bf(float f) {
    union { float f; unsigned u; } v; v.f = f;
    unsigned r = (v.u + 0x7FFFu + ((v.u >> 16) & 1u)) >> 16;   // round-to-nearest-even
    return (unsigned short)r;
}
__device__ __forceinline__ unsigned pack2bf(float a, float b) {
    return (unsigned)f2bf(a) | ((unsigned)f2bf(b) << 16);
}
__device__ __forceinline__ float bflo(unsigned u) { union { unsigned u; float f; } v; v.u = u << 16; return v.f; }
__device__ __forceinline__ float bfhi(unsigned u) { union { unsigned u; float f; } v; v.u = u & 0xffff0000u; return v.f; }

// ---------------- K0: mean-pool over T=4 + bf16 cast, padded [Mpad][320] ----------------
__global__ void pool_kernel(const float* __restrict__ x, unsigned short* __restrict__ xm,
                            int N, int Mpad) {
    int tid = blockIdx.x * 256 + threadIdx.x;
    if (tid >= Mpad * 40) return;
    int n = tid / 40, k8 = tid % 40;
    int k = k8 * 8;
    float v[8] = {0.f,0.f,0.f,0.f,0.f,0.f,0.f,0.f};
    if (n < N && k < 300) {
        const float* xp = x + (size_t)n * 1200 + k;
        #pragma unroll
        for (int t = 0; t < 4; ++t) {
            const float4 lo = *(const float4*)(xp + t * 300);
            v[0] += lo.x; v[1] += lo.y; v[2] += lo.z; v[3] += lo.w;
            if (k + 4 < 300) {   // k==296 tail: cols 300..303 stay zero
                const float4 hi = *(const float4*)(xp + t * 300 + 4);
                v[4] += hi.x; v[5] += hi.y; v[6] += hi.z; v[7] += hi.w;
            }
        }
    }
    union { unsigned short u[8]; bf16x8 vec; } p;
    #pragma unroll
    for (int j = 0; j < 8; ++j) p.u[j] = f2bf(v[j] * 0.25f);
    *(bf16x8*)(xm + (size_t)tid * 8) = p.vec;   // tid*8 == n*320 + k
}

// ---------------- setup: zero counters + weight prep (PRE-SWIZZLED) ----------------
// W [300][300] f32 -> Ws[ks][swizzled 16B-chunk]: panel ks holds cols c (<304), kk = k%32.
// Chunk-in-panel cp = c*4 + kk/8 is stored at cp' = cp ^ (c&7)  [XOR byte-bits 4-6].
// Round-8 counter SQ_LDS_BANK_CONFLICT=4.75M proved the linear layout is an 8-way
// conflict on ds_read_b128 (16-lane phase hits banks {0,16}+lhi*4 only). After swizzle
// each phase hits every bank exactly 2x (free, m136). Staging stays LINEAR (rule #21:
// pre-swizzled global source + linear global_load_lds + swizzled read).
__global__ void setup_kernel(const float* __restrict__ W1, const float* __restrict__ b1,
                             const float* __restrict__ W2, const float* __restrict__ b2,
                             unsigned short* __restrict__ Ws1, unsigned short* __restrict__ Ws2,
                             float* __restrict__ bp1, float* __restrict__ bp2,
                             int* __restrict__ deg, int* __restrict__ cnt, int* __restrict__ cur, int N) {
    int tid = blockIdx.x * 256 + threadIdx.x;
    if (tid < N) { deg[tid] = 0; cnt[tid] = 0; cur[tid] = 0; }
    if (tid < 304 * 320) {
        int c = tid / 320, k = tid % 320;
        int ks = k / 32, kk = k % 32;
        int cp  = c * 4 + (kk >> 3);             // 16B chunk within panel (0..1215)
        int cps = cp ^ (c & 7);                  // swizzled chunk (bijective)
        int dst = ks * 9728 + cps * 8 + (kk & 7);
        bool in = (c < 300) && (k < 300);
        Ws1[dst] = f2bf(in ? W1[c * 300 + k] : 0.f);
        Ws2[dst] = f2bf(in ? W2[c * 300 + k] : 0.f);
        if (tid < 304) { bp1[tid] = tid < 300 ? b1[tid] : 0.f; bp2[tid] = tid < 300 ? b2[tid] : 0.f; }
    }
}

// ---------------- degree (row/source) + in-degree counts (col/dest) ----------------
__global__ void degcnt_kernel(const int* __restrict__ ei, int E,
                              int* __restrict__ deg, int* __restrict__ cnt) {
    int e = blockIdx.x * 256 + threadIdx.x;
    if (e >= E) return;
    atomicAdd(&deg[ei[e]], 1);        // row
    atomicAdd(&cnt[ei[E + e]], 1);    // col
}

// ---------------- coalesced 3-phase scan: cnt -> indptr ----------------
__global__ void scanA_kernel(const int* __restrict__ cnt, int* __restrict__ bsum, int N) {
    __shared__ int sm[256];
    int i = blockIdx.x * 256 + threadIdx.x;
    sm[threadIdx.x] = (i < N) ? cnt[i] : 0;
    __syncthreads();
    for (int off = 128; off > 0; off >>= 1) {
        if (threadIdx.x < off) sm[threadIdx.x] += sm[threadIdx.x + off];
        __syncthreads();
    }
    if (threadIdx.x == 0) bsum[blockIdx.x] = sm[0];
}

__global__ void scanB_kernel(int* __restrict__ bsum, int nb, int* __restrict__ indptr, int N) {
    __shared__ int sm[256];
    int t = threadIdx.x;
    int v = (t < nb) ? bsum[t] : 0;
    sm[t] = v; __syncthreads();
    for (int off = 1; off < 256; off <<= 1) {
        int u = (t >= off) ? sm[t - off] : 0;
        __syncthreads();
        sm[t] += u;
        __syncthreads();
    }
    if (t < nb) bsum[t] = sm[t] - v;          // exclusive block offsets
    if (t == 255) indptr[N] = sm[255];        // total = E
}

__global__ void scanC_kernel(const int* __restrict__ cnt, const int* __restrict__ bsum,
                             int* __restrict__ indptr, const int* __restrict__ deg,
                             float* __restrict__ dis, int N) {
    __shared__ int sm[256];
    int i = blockIdx.x * 256 + threadIdx.x;
    int c = (i < N) ? cnt[i] : 0;
    sm[threadIdx.x] = c; __syncthreads();
    for (int off = 1; off < 256; off <<= 1) {
        int u = (threadIdx.x >= off) ? sm[threadIdx.x - off] : 0;
        __syncthreads();
        sm[threadIdx.x] += u;
        __syncthreads();
    }
    if (i < N) {
        indptr[i] = bsum[blockIdx.x] + sm[threadIdx.x] - c;   // exclusive prefix
        dis[i] = 1.0f / sqrtf((float)(deg[i] + 1));           // +1 self-loop
    }
}

// ---------------- CSR fill: csr[indptr[col]+slot] = row ----------------
__global__ void fill_kernel(const int* __restrict__ ei, int E,
                            const int* __restrict__ indptr, int* __restrict__ cur,
                            int* __restrict__ csr) {
    int e = blockIdx.x * 256 + threadIdx.x;
    if (e >= E) return;
    int r = ei[e], c = ei[E + e];
    int pos = indptr[c] + atomicAdd(&cur[c], 1);
    csr[pos] = r;
}

// ---------------- GEMM: g[n][o] = bf16(dis[n]*(A@W^T + b)) ----------------
// 512t / 8 waves / BM=128. Per K-step: ONE barrier; stage panel ks+1 via
// global_load_lds (linear, zero staging VGPRs, loads fly during MFMA phase);
// swizzled ds_read_b128 (bank-conflict-free); A prefetched depth-2.
// VGPR ~100 -> __launch_bounds__(512,4) -> 16 waves/CU (2 blocks).
__global__ __launch_bounds__(512, 4) void gemm_kernel(
    const unsigned short* __restrict__ A, const unsigned short* __restrict__ Ws,
    const float* __restrict__ bp, const float* __restrict__ dis,
    unsigned short* __restrict__ g, int N)
{
    __shared__ __align__(16) unsigned short lds[2][9728];   // 2 x 19456B
    const int t = threadIdx.x;
    const int lane = t & 63;
    const int wave = t >> 6;                 // 0..7
    const int l15 = lane & 15, lhi = lane >> 4;
    const int rowBase = blockIdx.x * 128 + wave * 16;

    const unsigned short* Ap = A + (size_t)(rowBase + l15) * 320 + lhi * 8;
    const uint4* Wsrc = (const uint4*)Ws;    // 1216 16B-chunks per panel

    // swizzled read base: fragment (col=cf*16+l15, kk=lhi*8) lives at chunk
    // cf*64 + ((l15*4+lhi) ^ (l15&7))  [matches setup's cp^(c&7), verified bijective]
    const int rb16 = (l15 * 4 + lhi) ^ (l15 & 7);

    // prologue: stage panel 0 -> lds[0] (19 groups of 64 chunks; wave-uniform lds base)
    for (int grp = wave; grp < 19; grp += 8)
        __builtin_amdgcn_global_load_lds(
            (const __attribute__((address_space(1))) unsigned*)(Wsrc + grp * 64 + lane),
            (__attribute__((address_space(3))) unsigned*)(&lds[0][0] + grp * 512),
            16, 0, 0);

    bf16x8 a0 = *(const bf16x8*)(Ap);
    bf16x8 a1 = *(const bf16x8*)(Ap + 32);

    f32x4 acc[19];
    #pragma unroll
    for (int i = 0; i < 19; ++i) acc[i] = (f32x4){0.f,0.f,0.f,0.f};

    #pragma unroll
    for (int ks = 0; ks < 10; ++ks) {
        __syncthreads();   // drains vmcnt: stage(ks) landed; lgkm: prior reads of dst buf done
        if (ks < 9) {      // issue next panel now; completes by next barrier, flies under MFMA
            const uint4* s = Wsrc + (ks + 1) * 1216;
            unsigned short* d = &lds[(ks + 1) & 1][0];
            for (int grp = wave; grp < 19; grp += 8)
                __builtin_amdgcn_global_load_lds(
                    (const __attribute__((address_space(1))) unsigned*)(s + grp * 64 + lane),
                    (__attribute__((address_space(3))) unsigned*)(d + grp * 512),
                    16, 0, 0);
        }
        const unsigned short* lb = &lds[ks & 1][0] + rb16 * 8;
        #pragma unroll
        for (int cf = 0; cf < 19; ++cf) {
            bf16x8 b = *(const bf16x8*)(lb + cf * 512);
            acc[cf] = __builtin_amdgcn_mfma_f32_16x16x32_bf16(a0, b, acc[cf], 0, 0, 0);
        }
        a0 = a1;
        if (ks < 8) a1 = *(const bf16x8*)(Ap + (ks + 2) * 32);
    }

    const int n0 = rowBase + lhi * 4;
    float dd[4];
    #pragma unroll
    for (int r = 0; r < 4; ++r) dd[r] = (n0 + r < N) ? dis[n0 + r] : 0.f;
    #pragma unroll
    for (int cf = 0; cf < 19; ++cf) {
        int o = cf * 16 + l15;
        if (o < 300) {
            float bo = bp[o];
            #pragma unroll
            for (int r = 0; r < 4; ++r)
                if (n0 + r < N) g[(size_t)(n0 + r) * 320 + o] = f2bf(dd[r] * (acc[cf][r] + bo));
        }
    }
}

// ---------------- propagate (bf16 g, pre-scaled by dis): out[i] = dis[i]*(g[i]+sum g[src]) ----------------
// One-issue row gather: padded row = 640B = 40 uint4; lanes 0..37 each read ONE uint4.
// Lane 37's top 8B are pad-col poison, masked at write. x4 neighbor unroll for MLP.
// MODE 0: f32 compact [N][300] to d_out. MODE 1: leaky_relu + bf16 padded [Mpad][320].
template<int MODE>
__global__ void prop_kernel(const unsigned short* __restrict__ g, const int* __restrict__ indptr,
                            const int* __restrict__ csr, const float* __restrict__ dis,
                            void* __restrict__ outp, int N, int Mpad) {
    int wave = threadIdx.x >> 6;
    int lane = threadIdx.x & 63;
    int n = blockIdx.x * 4 + wave;
    if (n >= (MODE ? Mpad : N)) return;
    const bool act = lane < 38;                    // 38*16B = 608B >= 600B of real cols
    float aL[4] = {0.f,0.f,0.f,0.f}, aH[4] = {0.f,0.f,0.f,0.f};
    if (n < N) {
        if (act) {
            uint4 u = *((const uint4*)(g + (size_t)n * 320) + lane);
            aL[0] = bflo(u.x); aH[0] = bfhi(u.x);
            aL[1] = bflo(u.y); aH[1] = bfhi(u.y);
            aL[2] = bflo(u.z); aH[2] = bfhi(u.z);
            aL[3] = bflo(u.w); aH[3] = bfhi(u.w);
        }
        int beg = indptr[n], end = indptr[n + 1];
        int j = beg;
        for (; j + 4 <= end; j += 4) {
            int s0 = csr[j], s1 = csr[j+1], s2 = csr[j+2], s3 = csr[j+3];
            const uint4* p0 = (const uint4*)(g + (size_t)s0 * 320) + lane;
            const uint4* p1 = (const uint4*)(g + (size_t)s1 * 320) + lane;
            const uint4* p2 = (const uint4*)(g + (size_t)s2 * 320) + lane;
            const uint4* p3 = (const uint4*)(g + (size_t)s3 * 320) + lane;
            if (act) {
                uint4 u0 = *p0, u1 = *p1, u2 = *p2, u3 = *p3;
                aL[0] += bflo(u0.x) + bflo(u1.x) + bflo(u2.x) + bflo(u3.x);
                aH[0] += bfhi(u0.x) + bfhi(u1.x) + bfhi(u2.x) + bfhi(u3.x);
                aL[1] += bflo(u0.y) + bflo(u1.y) + bflo(u2.y) + bflo(u3.y);
                aH[1] += bfhi(u0.y) + bfhi(u1.y) + bfhi(u2.y) + bfhi(u3.y);
                aL[2] += bflo(u0.z) + bflo(u1.z) + bflo(u2.z) + bflo(u3.z);
                aH[2] += bfhi(u0.z) + bfhi(u1.z) + bfhi(u2.z) + bfhi(u3.z);
                aL[3] += bflo(u0.w) + bflo(u1.w) + bflo(u2.w) + bflo(u3.w);
                aH[3] += bfhi(u0.w) + bfhi(u1.w) + bfhi(u2.w) + bfhi(u3.w);
            }
        }
        for (; j < end; ++j) {
            const uint4* ps = (const uint4*)(g + (size_t)csr[j] * 320) + lane;
            if (act) {
                uint4 u = *ps;
                aL[0] += bflo(u.x); aH[0] += bfhi(u.x);
                aL[1] += bflo(u.y); aH[1] += bfhi(u.y);
                aL[2] += bflo(u.z); aH[2] += bfhi(u.z);
                aL[3] += bflo(u.w); aH[3] += bfhi(u.w);
            }
        }
        float dn = dis[n];
        #pragma unroll
        for (int i = 0; i < 4; ++i) { aL[i] *= dn; aH[i] *= dn; }
    }
    if (MODE == 0) {
        // lane l covers f32 cols 8l..8l+7; lane 37 only 296..299 valid
        float* out = (float*)outp + (size_t)n * 300 + lane * 8;
        if (lane < 37) {
            float4 f0 = {aL[0], aH[0], aL[1], aH[1]};
            float4 f1 = {aL[2], aH[2], aL[3], aH[3]};
            *(float4*)out = f0;
            *(float4*)(out + 4) = f1;
        } else if (lane == 37) {
            float4 f0 = {aL[0], aH[0], aL[1], aH[1]};
            *(float4*)out = f0;
        }
    } else {
        uint4* h = (uint4*)((unsigned*)outp + (size_t)n * 160) + lane;
        if (lane < 40) {
            uint4 w = {0u, 0u, 0u, 0u};
            if (act) {
                float vL, vH;
                vL = aL[0]; vL = vL > 0.f ? vL : 0.01f * vL;
                vH = aH[0]; vH = vH > 0.f ? vH : 0.01f * vH;
                w.x = pack2bf(vL, vH);
                vL = aL[1]; vL = vL > 0.f ? vL : 0.01f * vL;
                vH = aH[1]; vH = vH > 0.f ? vH : 0.01f * vH;
                w.y = pack2bf(vL, vH);
                vL = aL[2]; vL = vL > 0.f ? vL : 0.01f * vL;
                vH = aH[2]; vH = vH > 0.f ? vH : 0.01f * vH;
                w.z = pack2bf(vL, vH);
                vL = aL[3]; vL = vL > 0.f ? vL : 0.01f * vL;
                vH = aH[3]; vH = vH > 0.f ? vH : 0.01f * vH;
                w.w = pack2bf(vL, vH);
                if (lane == 37) { w.z = 0u; w.w = 0u; }   // cols 300..303 = K-pad
            }
            *h = w;                                       // lanes 38,39 zero cols 304..319
        }
    }
}

extern "C" void kernel_launch(void* const* d_in, const int* in_sizes, int n_in,
                              void* d_out, int out_size, void* d_ws, size_t ws_size,
                              hipStream_t stream) {
    const float* x  = (const float*)d_in[0];
    const int*   ei = (const int*)d_in[1];
    const float* W1 = (const float*)d_in[2];
    const float* b1 = (const float*)d_in[3];
    const float* W2 = (const float*)d_in[4];
    const float* b2 = (const float*)d_in[5];
    float* out = (float*)d_out;

    const int N = in_sizes[0] / 1200;     // 50000
    const int E = in_sizes[1] / 2;        // 250000
    const int Mpad = ((N + 127) / 128) * 128;   // 50048 (multiple of 128)
    const int NB = (N + 255) / 256;       // 196 scan tiles

    // ---- carve workspace (256B aligned) ----
    char* p = (char*)d_ws;
    auto carve = [&](size_t bytes) -> char* {
        char* r = p; p += (bytes + 255) & ~(size_t)255; return r;
    };
    unsigned short* xm   = (unsigned short*)carve((size_t)Mpad * 320 * 2);  // 32 MB
    unsigned short* g1   = (unsigned short*)carve((size_t)Mpad * 320 * 2);  // 32 MB
    unsigned short* hb   = (unsigned short*)carve((size_t)Mpad * 320 * 2);  // 32 MB
    unsigned short* g2   = (unsigned short*)carve((size_t)Mpad * 320 * 2);  // 32 MB
    float* dis           = (float*)carve((size_t)N * 4);
    int* deg             = (int*)carve((size_t)N * 4);
    int* cnt             = (int*)carve((size_t)N * 4);
    int* indptr          = (int*)carve((size_t)(N + 1) * 4);
    int* cur             = (int*)carve((size_t)N * 4);
    int* csr             = (int*)carve((size_t)E * 4);
    int* bsum            = (int*)carve(256 * 4);
    unsigned short* Ws1  = (unsigned short*)carve(304 * 320 * 2);   // pre-swizzled [10][1216 chunks]
    unsigned short* Ws2  = (unsigned short*)carve(304 * 320 * 2);
    float* bp1           = (float*)carve(304 * 4);
    float* bp2           = (float*)carve(304 * 4);

    setup_kernel <<<(304 * 320 + 255) / 256, 256, 0, stream>>>(W1, b1, W2, b2, Ws1, Ws2, bp1, bp2,
                                                               deg, cnt, cur, N);
    pool_kernel  <<<(Mpad * 40 + 255) / 256, 256, 0, stream>>>(x, xm, N, Mpad);
    degcnt_kernel<<<(E + 255) / 256, 256, 0, stream>>>(ei, E, deg, cnt);
    scanA_kernel <<<NB, 256, 0, stream>>>(cnt, bsum, N);
    scanB_kernel <<<1, 256, 0, stream>>>(bsum, NB, indptr, N);
    scanC_kernel <<<NB, 256, 0, stream>>>(cnt, bsum, indptr, deg, dis, N);
    fill_kernel  <<<(E + 255) / 256, 256, 0, stream>>>(ei, E, indptr, cur, csr);

    // layer 1: g1 = bf16(dis*(xm@W1^T + b1)); prop+leaky -> hb (bf16 padded)
    gemm_kernel  <<<Mpad / 128, 512, 0, stream>>>(xm, Ws1, bp1, dis, g1, N);
    prop_kernel<1><<<Mpad / 4, 256, 0, stream>>>(g1, indptr, csr, dis, hb, N, Mpad);
    // layer 2: g2 = bf16(dis*(hb@W2^T + b2)); final prop -> d_out (f32)
    gemm_kernel  <<<Mpad / 128, 512, 0, stream>>>(hb, Ws2, bp2, dis, g2, N);
    prop_kernel<0><<<(N + 3) / 4, 256, 0, stream>>>(g2, indptr, csr, dis, out, N, Mpad);
}